// Round 12
// baseline (243.352 us; speedup 1.0000x reference)
//
#include <hip/hip_runtime.h>

// Problem constants (match reference)
#define BQ 512
#define AQ 32
#define DQ 256
#define NQ (BQ * AQ)      // 16384 nodes
#define EQ 1048576        // edges
#define THR 0.5f
#define EPSF 1e-5f
#define DEG_STRIDE 160    // padded bucket row; deg ~ Binom(E,1/N) mean 64, +12 sigma
#define BIN_TGTS 64       // targets per bin
#define NBINS (NQ / BIN_TGTS)          // 256
#define BIN_STRIDE 4864   // mean 4096 edges/bin, sigma ~64, +12 sigma
#define HD 128            // half feature dim (one plane)

typedef __attribute__((ext_vector_type(8))) short bf16x8;
typedef __attribute__((ext_vector_type(4))) float f32x4;

// fp32 -> bf16 round-to-nearest-even (finite inputs)
__device__ __forceinline__ unsigned short f2bf(float f) {
    unsigned int u = __float_as_uint(f);
    return (unsigned short)((u + 0x7FFFu + ((u >> 16) & 1u)) >> 16);
}
__device__ __forceinline__ float bf2f(unsigned short h) {
    return __uint_as_float((unsigned int)h << 16);
}

// ---------------------------------------------------------------------------
// Fused dispatch 1 (independent slices; bin_cursor pre-zeroed by memset):
//  blocks [0,256):    W [K,N] fp32 -> Wt hi/lo [N,K] bf16 split
//  blocks [256,512):  partition edges into 256 target-range bins, packed
//                     (t<<14|s); LDS histogram -> one global reservation per
//                     bin -> bin-grouped line-local writes.
// ---------------------------------------------------------------------------
__global__ __launch_bounds__(256) void k_prep_part(
        const float* __restrict__ W, unsigned short* __restrict__ Wt,
        const int* __restrict__ src, const int* __restrict__ tgt,
        int* __restrict__ bin_cursor, unsigned int* __restrict__ binned) {
    __shared__ int hist[NBINS];
    int tid = threadIdx.x;
    if (blockIdx.x < 256) {
        int idx = blockIdx.x * 256 + tid;       // covers DQ*DQ
        int n = idx >> 8;
        int k = idx & 255;
        float w = W[k * DQ + n];
        unsigned short h = f2bf(w);
        Wt[idx] = h;                            // hi plane
        Wt[DQ * DQ + idx] = f2bf(w - bf2f(h));  // lo plane
        return;
    }
    // ---- edge partition ----
    hist[tid] = 0;
    __syncthreads();
    int base = (blockIdx.x - 256) * 4096;
    int t[16], s[16];
    #pragma unroll
    for (int i = 0; i < 16; i++) {
        int e = base + i * 256 + tid;
        t[i] = tgt[e];
        s[i] = src[e];
        atomicAdd(&hist[t[i] >> 6], 1);
    }
    __syncthreads();
    int mine = hist[tid];
    __syncthreads();
    hist[tid] = tid * BIN_STRIDE + atomicAdd(&bin_cursor[tid], mine);
    __syncthreads();
    #pragma unroll
    for (int i = 0; i < 16; i++) {
        int slot = atomicAdd(&hist[t[i] >> 6], 1);
        binned[slot] = ((unsigned int)t[i] << 14) | (unsigned int)s[i];
    }
}

// ---------------------------------------------------------------------------
// Fused dispatch 2 (independent slices, both depend only on dispatch 1):
//  blocks [0,256):    per-bin bucket build in LDS, coalesced write-out,
//                     cnt + precomputed fp32 dinv
//  blocks [256,512):  bf16x3 split MFMA GEMM xwb = bf16(X @ W), stored as two
//                     4MB planes (dims 0-127 / 128-255) for L2-resident gather
// ---------------------------------------------------------------------------
__global__ __launch_bounds__(256) void k_bucket_gemm(
        const float* __restrict__ Xp, const unsigned short* __restrict__ Wt,
        unsigned short* __restrict__ xwb,
        const int* __restrict__ bin_cursor, const unsigned int* __restrict__ binned,
        unsigned short* __restrict__ bucket, int* __restrict__ cnt,
        float* __restrict__ dinv) {
    __shared__ unsigned short lbuck[BIN_TGTS * DEG_STRIDE];  // 20 KB
    __shared__ int lcnt[BIN_TGTS];
    int tid = threadIdx.x;
    if (blockIdx.x < NBINS) {
        // ---- bucket build ----
        int b = blockIdx.x;
        if (tid < BIN_TGTS) lcnt[tid] = 0;
        __syncthreads();
        int beg = b * BIN_STRIDE;
        int count = bin_cursor[b];
        if (count > BIN_STRIDE) count = BIN_STRIDE;
        int end = beg + count;
        for (int i = beg + tid; i < end; i += 256) {
            unsigned int ed = binned[i];
            int tl = (int)(ed >> 14) & 63;
            int pos = atomicAdd(&lcnt[tl], 1);
            if (pos < DEG_STRIDE)
                lbuck[tl * DEG_STRIDE + pos] = (unsigned short)(ed & 0x3FFFu);
        }
        __syncthreads();
        const unsigned int* lb32 = (const unsigned int*)lbuck;   // 5120 uints
        unsigned int* gb32 = (unsigned int*)(bucket + (size_t)b * BIN_TGTS * DEG_STRIDE);
        #pragma unroll
        for (int i = 0; i < 20; i++) gb32[i * 256 + tid] = lb32[i * 256 + tid];
        if (tid < BIN_TGTS) {
            int c = lcnt[tid];
            cnt[b * BIN_TGTS + tid] = c;
            dinv[b * BIN_TGTS + tid] = rsqrtf((float)(c + 1));
        }
        return;
    }
    // ---- bf16x3 split MFMA GEMM ----
    // A frag: A[m=lane&15][k=quad*8+j]; B frag from Wt[n][k]; C/D row=quad*4+r,
    // col=lane&15 (verified rounds 5-10).
    int wave = tid >> 6;
    int lane = tid & 63;
    int col = lane & 15;
    int quad = lane >> 4;
    int mbase = (blockIdx.x - NBINS) * 64 + wave * 16;
    int m = mbase + col;

    const float* arow = Xp + (size_t)m * DQ;
    const unsigned short* Wlo = Wt + DQ * DQ;

    f32x4 acc[16];
    f32x4 zero = {0.f, 0.f, 0.f, 0.f};
    #pragma unroll
    for (int i = 0; i < 16; i++) acc[i] = zero;

    for (int k0 = 0; k0 < DQ; k0 += 32) {
        int kq = k0 + quad * 8;
        float4 a0 = *(const float4*)(arow + kq);
        float4 a1 = *(const float4*)(arow + kq + 4);
        float av[8] = {a0.x, a0.y, a0.z, a0.w, a1.x, a1.y, a1.z, a1.w};
        bf16x8 ah, al;
        #pragma unroll
        for (int j = 0; j < 8; j++) {
            unsigned short h = f2bf(av[j]);
            ah[j] = (short)h;
            al[j] = (short)f2bf(av[j] - bf2f(h));
        }
        #pragma unroll
        for (int nt = 0; nt < 16; nt++) {
            size_t boff = (size_t)(nt * 16 + col) * DQ + kq;
            bf16x8 bh = *(const bf16x8*)(Wt + boff);
            bf16x8 bl = *(const bf16x8*)(Wlo + boff);
            acc[nt] = __builtin_amdgcn_mfma_f32_16x16x32_bf16(ah, bh, acc[nt], 0, 0, 0);
            acc[nt] = __builtin_amdgcn_mfma_f32_16x16x32_bf16(al, bh, acc[nt], 0, 0, 0);
            acc[nt] = __builtin_amdgcn_mfma_f32_16x16x32_bf16(ah, bl, acc[nt], 0, 0, 0);
        }
    }

    #pragma unroll
    for (int nt = 0; nt < 16; nt++) {
        int gc = nt * 16 + col;
        unsigned short* dst = xwb + (size_t)(gc >> 7) * NQ * HD;  // plane 0/1
        int c = gc & (HD - 1);
        #pragma unroll
        for (int r = 0; r < 4; r++) {
            dst[(size_t)(mbase + quad * 4 + r) * HD + c] = f2bf(acc[nt][r]);
        }
    }
}

// ---------------------------------------------------------------------------
// GCN aggregation, split-D split-wave: blocks [0,4096) = plane 0 (dims
// 0-127, 4MB = one XCD L2), [4096,8192) = plane 1. Within a wave, lanes
// 0-31 process even edges, 32-63 odd edges: one uint2 wave-load covers
// 2 edges x 256B row (8 B/lane). Edge index + fp32 coef come from
// uniform-address broadcast loads (no shfls in the loop). Partial sums
// merged with one __shfl(lane^32) at the end.
// NOTE (round-11 bug): xwb param is uint*, so the plane offset must be in
// UINT units: one plane = NQ rows x 64 uints = NQ*(HD/2). Round 11 used
// NQ*HD (ushort units) -> plane 1 read 4MB past xwb -> NaN garbage.
// ---------------------------------------------------------------------------
__global__ __launch_bounds__(256) void k_agg(const unsigned int* __restrict__ xwb,
                                             const int* __restrict__ cnt,
                                             const unsigned short* __restrict__ bucket,
                                             const float* __restrict__ dinv,
                                             const float* __restrict__ bias,
                                             float* __restrict__ out) {
    int wave = threadIdx.x >> 6;              // 0..3
    int lane = threadIdx.x & 63;
    int sub  = lane >> 5;                     // edge-of-pair selector
    int sl   = lane & 31;                     // slot within sub-wave
    int half = blockIdx.x >> 12;              // plane 0 or 1
    int t = (blockIdx.x & 4095) * 4 + wave;
    // plane offset in UINT units: NQ * (HD/2) uints = 4 MB per plane
    const uint2* plane = (const uint2*)(xwb + (size_t)half * NQ * (HD / 2));

    float dt = dinv[t];
    float cself = sub ? 0.f : dt * dt;        // self term counted once
    uint2 sp = plane[(size_t)t * 32 + sl];
    float4 acc;
    acc.x = __uint_as_float(sp.x << 16) * cself;
    acc.y = __uint_as_float(sp.x & 0xFFFF0000u) * cself;
    acc.z = __uint_as_float(sp.y << 16) * cself;
    acc.w = __uint_as_float(sp.y & 0xFFFF0000u) * cself;

    const unsigned short* brow = bucket + t * DEG_STRIDE;
    int num = cnt[t];
    if (num > DEG_STRIDE) num = DEG_STRIDE;   // safety clamp (never expected)
    for (int j0 = 0; j0 < num; j0 += 16) {    // 8 pairs per unrolled block
        #pragma unroll
        for (int jj = 0; jj < 16; jj += 2) {
            int j = j0 + jj + sub;
            int jv = j < num ? j : num - 1;   // clamped (L1-hot) pad load
            int e = (int)brow[jv];            // broadcast within sub-wave
            float c = (j < num) ? dinv[e] * dt : 0.f;
            uint2 p = plane[(size_t)e * 32 + sl];
            acc.x += __uint_as_float(p.x << 16) * c;
            acc.y += __uint_as_float(p.x & 0xFFFF0000u) * c;
            acc.z += __uint_as_float(p.y << 16) * c;
            acc.w += __uint_as_float(p.y & 0xFFFF0000u) * c;
        }
    }

    // merge even/odd partials across the two sub-waves
    acc.x += __shfl(acc.x, lane ^ 32);
    acc.y += __shfl(acc.y, lane ^ 32);
    acc.z += __shfl(acc.z, lane ^ 32);
    acc.w += __shfl(acc.w, lane ^ 32);

    if (sub == 0) {
        float4 bv = ((const float4*)bias)[half * 32 + sl];
        acc.x += bv.x; acc.y += bv.y; acc.z += bv.z; acc.w += bv.w;
        ((float4*)out)[(size_t)t * 64 + half * 32 + sl] = acc;
    }
}

// ---------------------------------------------------------------------------
// Per-batch pairwise sq-dist scores -> row min-max normalize -> threshold.
// One block per batch clip. xi register-chunked (8 float4) across the 4 j's.
// ---------------------------------------------------------------------------
__global__ __launch_bounds__(256) void k_scores(const float* __restrict__ xo,
                                                float* __restrict__ mask) {
    __shared__ float xs[AQ][DQ + 4];   // +4: 16B-aligned rows, bank-stride 4
    __shared__ float sq[AQ];
    __shared__ float sc[AQ][AQ + 1];   // +1: break 32-stride on row scans
    __shared__ float rmin[AQ], rmax[AQ];

    int bq = blockIdx.x;
    int tid = threadIdx.x;
    const float* xb = xo + (size_t)bq * AQ * DQ;

    for (int idx = tid; idx < AQ * DQ; idx += 256) {
        xs[idx >> 8][idx & 255] = xb[idx];
    }
    __syncthreads();

    if (tid < AQ) {
        const float4* xi = (const float4*)xs[tid];
        float s = 0.f;
        #pragma unroll 8
        for (int dd = 0; dd < DQ / 4; dd++) {
            float4 a = xi[dd];
            s += a.x * a.x + a.y * a.y + a.z * a.z + a.w * a.w;
        }
        sq[tid] = s;
    }
    __syncthreads();

    // 4 consecutive (i,j) pairs per thread; i constant within the quad
    {
        int p0 = tid * 4;
        int i = p0 >> 5;
        int j0 = p0 & 31;
        const float4* xi = (const float4*)xs[i];
        float g[4] = {0.f, 0.f, 0.f, 0.f};
        for (int dd = 0; dd < DQ / 4; dd += 8) {
            float4 ar[8];
            #pragma unroll
            for (int u = 0; u < 8; u++) ar[u] = xi[dd + u];
            #pragma unroll
            for (int q = 0; q < 4; q++) {
                const float4* xj = (const float4*)xs[j0 + q];
                float gq = 0.f;
                #pragma unroll
                for (int u = 0; u < 8; u++) {
                    float4 b = xj[dd + u];
                    gq += ar[u].x * b.x + ar[u].y * b.y +
                          ar[u].z * b.z + ar[u].w * b.w;
                }
                g[q] += gq;
            }
        }
        #pragma unroll
        for (int q = 0; q < 4; q++) {
            sc[i][j0 + q] = sq[i] - 2.f * g[q] + sq[j0 + q];
        }
    }
    __syncthreads();

    if (tid < AQ) {
        float mn = sc[tid][0], mx = sc[tid][0];
        for (int j = 1; j < AQ; j++) {
            float v = sc[tid][j];
            mn = fminf(mn, v);
            mx = fmaxf(mx, v);
        }
        rmin[tid] = mn;
        rmax[tid] = mx;
    }
    __syncthreads();

    float* mb = mask + (size_t)bq * AQ * AQ;
    #pragma unroll
    for (int q = 0; q < 4; q++) {
        int p = tid * 4 + q;
        int i = p >> 5, j = p & 31;
        float v = (sc[i][j] - rmin[i]) / (rmax[i] - rmin[i] + EPSF);
        mb[p] = (v > THR) ? 1.0f : 0.0f;
    }
}

// ---------------------------------------------------------------------------
extern "C" void kernel_launch(void* const* d_in, const int* in_sizes, int n_in,
                              void* d_out, int out_size, void* d_ws, size_t ws_size,
                              hipStream_t stream) {
    const float* X    = (const float*)d_in[0];   // [B,A,D]
    const int*   ei   = (const int*)d_in[1];     // [2,E]
    const float* W    = (const float*)d_in[2];   // [D,D]
    const float* bias = (const float*)d_in[3];   // [D]
    float* out = (float*)d_out;                  // [N*D] Xo  ++  [B*A*A] mask

    char* ws = (char*)d_ws;
    unsigned short* xwb = (unsigned short*)ws;                            // 8 MB (2 planes)
    unsigned short* bucket = (unsigned short*)(ws + (size_t)NQ * DQ * 2); // 5.25 MB
    unsigned int* binned = (unsigned int*)(bucket + (size_t)NQ * DEG_STRIDE); // 4.98 MB
    unsigned short* Wt = (unsigned short*)(binned + (size_t)NBINS * BIN_STRIDE); // 256 KB
    int* cnt = (int*)(Wt + 2 * DQ * DQ);                                  // 64 KB
    float* dinv = (float*)(cnt + NQ);                                     // 64 KB
    int* bin_cursor = (int*)(dinv + NQ);                                  // 1 KB

    const int* src = ei;
    const int* tgt = ei + EQ;

    hipMemsetAsync(bin_cursor, 0, NBINS * sizeof(int), stream);
    k_prep_part<<<512, 256, 0, stream>>>(W, Wt, src, tgt, bin_cursor, binned);
    k_bucket_gemm<<<512, 256, 0, stream>>>(X, Wt, xwb, bin_cursor, binned,
                                           bucket, cnt, dinv);
    k_agg<<<2 * NQ / 4, 256, 0, stream>>>((const unsigned int*)xwb, cnt, bucket,
                                          dinv, bias, out);
    k_scores<<<BQ, 256, 0, stream>>>(out, out + (size_t)NQ * DQ);
}

// Round 13
// 190.339 us; speedup vs baseline: 1.2785x; 1.2785x over previous
//
#include <hip/hip_runtime.h>

// Problem constants (match reference)
#define BQ 512
#define AQ 32
#define DQ 256
#define NQ (BQ * AQ)      // 16384 nodes
#define EQ 1048576        // edges
#define THR 0.5f
#define EPSF 1e-5f
#define DEG_STRIDE 160    // padded bucket row; deg ~ Binom(E,1/N) mean 64, +12 sigma
#define BIN_TGTS 64       // targets per bin
#define NBINS (NQ / BIN_TGTS)          // 256
#define BIN_STRIDE 4864   // mean 4096 edges/bin, sigma ~64, +12 sigma

typedef __attribute__((ext_vector_type(8))) short bf16x8;
typedef __attribute__((ext_vector_type(4))) float f32x4;

// fp32 -> bf16 round-to-nearest-even (finite inputs)
__device__ __forceinline__ unsigned short f2bf(float f) {
    unsigned int u = __float_as_uint(f);
    return (unsigned short)((u + 0x7FFFu + ((u >> 16) & 1u)) >> 16);
}
__device__ __forceinline__ float bf2f(unsigned short h) {
    return __uint_as_float((unsigned int)h << 16);
}

// ---------------------------------------------------------------------------
// Fused dispatch 1 (independent slices; bin_cursor pre-zeroed by memset):
//  blocks [0,256):    W [K,N] fp32 -> Wt hi/lo [N,K] bf16 split
//  blocks [256,512):  partition edges into 256 target-range bins, packed
//                     (t<<14|s); LDS histogram -> one global reservation per
//                     bin -> bin-grouped line-local writes.
// ---------------------------------------------------------------------------
__global__ __launch_bounds__(256) void k_prep_part(
        const float* __restrict__ W, unsigned short* __restrict__ Wt,
        const int* __restrict__ src, const int* __restrict__ tgt,
        int* __restrict__ bin_cursor, unsigned int* __restrict__ binned) {
    __shared__ int hist[NBINS];
    int tid = threadIdx.x;
    if (blockIdx.x < 256) {
        int idx = blockIdx.x * 256 + tid;       // covers DQ*DQ
        int n = idx >> 8;
        int k = idx & 255;
        float w = W[k * DQ + n];
        unsigned short h = f2bf(w);
        Wt[idx] = h;                            // hi plane
        Wt[DQ * DQ + idx] = f2bf(w - bf2f(h));  // lo plane
        return;
    }
    // ---- edge partition ----
    hist[tid] = 0;
    __syncthreads();
    int base = (blockIdx.x - 256) * 4096;
    int t[16], s[16];
    #pragma unroll
    for (int i = 0; i < 16; i++) {
        int e = base + i * 256 + tid;
        t[i] = tgt[e];
        s[i] = src[e];
        atomicAdd(&hist[t[i] >> 6], 1);
    }
    __syncthreads();
    int mine = hist[tid];
    __syncthreads();
    hist[tid] = tid * BIN_STRIDE + atomicAdd(&bin_cursor[tid], mine);
    __syncthreads();
    #pragma unroll
    for (int i = 0; i < 16; i++) {
        int slot = atomicAdd(&hist[t[i] >> 6], 1);
        binned[slot] = ((unsigned int)t[i] << 14) | (unsigned int)s[i];
    }
}

// ---------------------------------------------------------------------------
// Fused dispatch 2 (independent slices, both depend only on dispatch 1):
//  blocks [0,256):    per-bin bucket build in LDS, coalesced write-out,
//                     cnt + precomputed fp32 dinv
//  blocks [256,512):  bf16x3 split MFMA GEMM xwb = bf16(X @ W), single
//                     contiguous [NQ][256] bf16 layout (8 MB)
// ---------------------------------------------------------------------------
__global__ __launch_bounds__(256) void k_bucket_gemm(
        const float* __restrict__ Xp, const unsigned short* __restrict__ Wt,
        unsigned short* __restrict__ xwb,
        const int* __restrict__ bin_cursor, const unsigned int* __restrict__ binned,
        unsigned short* __restrict__ bucket, int* __restrict__ cnt,
        float* __restrict__ dinv) {
    __shared__ unsigned short lbuck[BIN_TGTS * DEG_STRIDE];  // 20 KB
    __shared__ int lcnt[BIN_TGTS];
    int tid = threadIdx.x;
    if (blockIdx.x < NBINS) {
        // ---- bucket build ----
        int b = blockIdx.x;
        if (tid < BIN_TGTS) lcnt[tid] = 0;
        __syncthreads();
        int beg = b * BIN_STRIDE;
        int count = bin_cursor[b];
        if (count > BIN_STRIDE) count = BIN_STRIDE;
        int end = beg + count;
        for (int i = beg + tid; i < end; i += 256) {
            unsigned int ed = binned[i];
            int tl = (int)(ed >> 14) & 63;
            int pos = atomicAdd(&lcnt[tl], 1);
            if (pos < DEG_STRIDE)
                lbuck[tl * DEG_STRIDE + pos] = (unsigned short)(ed & 0x3FFFu);
        }
        __syncthreads();
        const unsigned int* lb32 = (const unsigned int*)lbuck;   // 5120 uints
        unsigned int* gb32 = (unsigned int*)(bucket + (size_t)b * BIN_TGTS * DEG_STRIDE);
        #pragma unroll
        for (int i = 0; i < 20; i++) gb32[i * 256 + tid] = lb32[i * 256 + tid];
        if (tid < BIN_TGTS) {
            int c = lcnt[tid];
            cnt[b * BIN_TGTS + tid] = c;
            dinv[b * BIN_TGTS + tid] = rsqrtf((float)(c + 1));
        }
        return;
    }
    // ---- bf16x3 split MFMA GEMM ----
    // A frag: A[m=lane&15][k=quad*8+j]; B frag from Wt[n][k]; C/D row=quad*4+r,
    // col=lane&15 (verified rounds 5-12).
    int wave = tid >> 6;
    int lane = tid & 63;
    int col = lane & 15;
    int quad = lane >> 4;
    int mbase = (blockIdx.x - NBINS) * 64 + wave * 16;
    int m = mbase + col;

    const float* arow = Xp + (size_t)m * DQ;
    const unsigned short* Wlo = Wt + DQ * DQ;

    f32x4 acc[16];
    f32x4 zero = {0.f, 0.f, 0.f, 0.f};
    #pragma unroll
    for (int i = 0; i < 16; i++) acc[i] = zero;

    for (int k0 = 0; k0 < DQ; k0 += 32) {
        int kq = k0 + quad * 8;
        float4 a0 = *(const float4*)(arow + kq);
        float4 a1 = *(const float4*)(arow + kq + 4);
        float av[8] = {a0.x, a0.y, a0.z, a0.w, a1.x, a1.y, a1.z, a1.w};
        bf16x8 ah, al;
        #pragma unroll
        for (int j = 0; j < 8; j++) {
            unsigned short h = f2bf(av[j]);
            ah[j] = (short)h;
            al[j] = (short)f2bf(av[j] - bf2f(h));
        }
        #pragma unroll
        for (int nt = 0; nt < 16; nt++) {
            size_t boff = (size_t)(nt * 16 + col) * DQ + kq;
            bf16x8 bh = *(const bf16x8*)(Wt + boff);
            bf16x8 bl = *(const bf16x8*)(Wlo + boff);
            acc[nt] = __builtin_amdgcn_mfma_f32_16x16x32_bf16(ah, bh, acc[nt], 0, 0, 0);
            acc[nt] = __builtin_amdgcn_mfma_f32_16x16x32_bf16(al, bh, acc[nt], 0, 0, 0);
            acc[nt] = __builtin_amdgcn_mfma_f32_16x16x32_bf16(ah, bl, acc[nt], 0, 0, 0);
        }
    }

    #pragma unroll
    for (int nt = 0; nt < 16; nt++) {
        #pragma unroll
        for (int r = 0; r < 4; r++) {
            xwb[(size_t)(mbase + quad * 4 + r) * DQ + nt * 16 + col] =
                f2bf(acc[nt][r]);
        }
    }
}

// ---------------------------------------------------------------------------
// GCN aggregation — round-8 structure (best measured: 51.6 us). Wave per
// target: 64 lanes x uint2 (4 bf16) = one 512B row per global_load_dwordx2.
// 64 indices+coefs prefetched coalesced OUTSIDE the inner loop, broadcast
// via shfl (register op): inner loop has exactly ONE memory op per edge
// (round-12 lesson: broadcast LOADS create a dependent chain and cost 2x).
// fp32 coef/accumulate (round-9 lesson: bf16 storage consumes the budget).
// ---------------------------------------------------------------------------
__global__ __launch_bounds__(256) void k_agg(const unsigned int* __restrict__ xwb,
                                             const int* __restrict__ cnt,
                                             const unsigned short* __restrict__ bucket,
                                             const float* __restrict__ dinv,
                                             const float* __restrict__ bias,
                                             float* __restrict__ out) {
    int wave = threadIdx.x >> 6;              // 0..3
    int lane = threadIdx.x & 63;
    int t = blockIdx.x * 4 + wave;            // grid = NQ/4 blocks
    const uint2* xw2 = (const uint2*)xwb;     // 64 uint2 per row

    float dt = dinv[t];
    float c0 = dt * dt;
    uint2 sp = xw2[(size_t)t * 64 + lane];
    float4 acc;
    acc.x = __uint_as_float(sp.x << 16) * c0;
    acc.y = __uint_as_float(sp.x & 0xFFFF0000u) * c0;
    acc.z = __uint_as_float(sp.y << 16) * c0;
    acc.w = __uint_as_float(sp.y & 0xFFFF0000u) * c0;

    const unsigned short* brow = bucket + t * DEG_STRIDE;
    int num = cnt[t];
    if (num > DEG_STRIDE) num = DEG_STRIDE;   // safety clamp (never expected)
    for (int k0 = 0; k0 < num; k0 += 64) {
        int rem = num - k0;
        int n = rem < 64 ? rem : 64;
        int idx = k0 + (lane < n ? lane : 0);
        int e = (int)brow[idx];               // coalesced 2B/lane prefetch
        float cl = (lane < n) ? dinv[e] * dt : 0.f;
        int n8 = (n + 7) & ~7;                // round up; c=0 pads are cheap
        for (int j0 = 0; j0 < n8; j0 += 8) {
            #pragma unroll
            for (int jj = 0; jj < 8; jj++) {
                int j = j0 + jj;
                int s = __shfl(e, j);
                float c = __shfl(cl, j);
                uint2 p = xw2[(size_t)s * 64 + lane];
                acc.x += __uint_as_float(p.x << 16) * c;
                acc.y += __uint_as_float(p.x & 0xFFFF0000u) * c;
                acc.z += __uint_as_float(p.y << 16) * c;
                acc.w += __uint_as_float(p.y & 0xFFFF0000u) * c;
            }
        }
    }

    float4 bv = ((const float4*)bias)[lane];
    acc.x += bv.x; acc.y += bv.y; acc.z += bv.z; acc.w += bv.w;
    ((float4*)out)[(size_t)t * 64 + lane] = acc;
}

// ---------------------------------------------------------------------------
// Per-batch pairwise sq-dist scores -> row min-max normalize -> threshold.
// One block per batch clip. float4 staging + float4 mask stores.
// ---------------------------------------------------------------------------
__global__ __launch_bounds__(256) void k_scores(const float* __restrict__ xo,
                                                float* __restrict__ mask) {
    __shared__ float xs[AQ][DQ + 4];   // +4: rows stay 16B-aligned (260*4B)
    __shared__ float sq[AQ];
    __shared__ float sc[AQ][AQ + 1];   // +1: break 32-stride on row scans
    __shared__ float rmin[AQ], rmax[AQ];

    int bq = blockIdx.x;
    int tid = threadIdx.x;
    const float* xb = xo + (size_t)bq * AQ * DQ;

    // 2048 float4s, 8 per thread, coalesced
    #pragma unroll
    for (int k = 0; k < 8; k++) {
        int fidx = k * 256 + tid;
        float4 v = ((const float4*)xb)[fidx];
        *(float4*)&xs[fidx >> 6][(fidx & 63) * 4] = v;
    }
    __syncthreads();

    if (tid < AQ) {
        const float4* xi = (const float4*)xs[tid];
        float s = 0.f;
        #pragma unroll 8
        for (int dd = 0; dd < DQ / 4; dd++) {
            float4 a = xi[dd];
            s += a.x * a.x + a.y * a.y + a.z * a.z + a.w * a.w;
        }
        sq[tid] = s;
    }
    __syncthreads();

    // 4 consecutive (i,j) pairs per thread; i constant within the quad
    {
        int p0 = tid * 4;
        int i = p0 >> 5;
        int j0 = p0 & 31;
        const float4* xi = (const float4*)xs[i];
        float g[4] = {0.f, 0.f, 0.f, 0.f};
        for (int dd = 0; dd < DQ / 4; dd += 8) {
            float4 ar[8];
            #pragma unroll
            for (int u = 0; u < 8; u++) ar[u] = xi[dd + u];
            #pragma unroll
            for (int q = 0; q < 4; q++) {
                const float4* xj = (const float4*)xs[j0 + q];
                float gq = 0.f;
                #pragma unroll
                for (int u = 0; u < 8; u++) {
                    float4 b = xj[dd + u];
                    gq += ar[u].x * b.x + ar[u].y * b.y +
                          ar[u].z * b.z + ar[u].w * b.w;
                }
                g[q] += gq;
            }
        }
        #pragma unroll
        for (int q = 0; q < 4; q++) {
            sc[i][j0 + q] = sq[i] - 2.f * g[q] + sq[j0 + q];
        }
    }
    __syncthreads();

    if (tid < AQ) {
        float mn = sc[tid][0], mx = sc[tid][0];
        for (int j = 1; j < AQ; j++) {
            float v = sc[tid][j];
            mn = fminf(mn, v);
            mx = fmaxf(mx, v);
        }
        rmin[tid] = mn;
        rmax[tid] = mx;
    }
    __syncthreads();

    float* mb = mask + (size_t)bq * AQ * AQ;
    {
        int p0 = tid * 4;
        int i = p0 >> 5, j0 = p0 & 31;
        float inv = 1.0f / (rmax[i] - rmin[i] + EPSF);
        float4 mv;
        mv.x = ((sc[i][j0 + 0] - rmin[i]) * inv > THR) ? 1.0f : 0.0f;
        mv.y = ((sc[i][j0 + 1] - rmin[i]) * inv > THR) ? 1.0f : 0.0f;
        mv.z = ((sc[i][j0 + 2] - rmin[i]) * inv > THR) ? 1.0f : 0.0f;
        mv.w = ((sc[i][j0 + 3] - rmin[i]) * inv > THR) ? 1.0f : 0.0f;
        ((float4*)mb)[tid] = mv;
    }
}

// ---------------------------------------------------------------------------
extern "C" void kernel_launch(void* const* d_in, const int* in_sizes, int n_in,
                              void* d_out, int out_size, void* d_ws, size_t ws_size,
                              hipStream_t stream) {
    const float* X    = (const float*)d_in[0];   // [B,A,D]
    const int*   ei   = (const int*)d_in[1];     // [2,E]
    const float* W    = (const float*)d_in[2];   // [D,D]
    const float* bias = (const float*)d_in[3];   // [D]
    float* out = (float*)d_out;                  // [N*D] Xo  ++  [B*A*A] mask

    char* ws = (char*)d_ws;
    unsigned short* xwb = (unsigned short*)ws;                            // 8 MB
    unsigned short* bucket = (unsigned short*)(ws + (size_t)NQ * DQ * 2); // 5.25 MB
    unsigned int* binned = (unsigned int*)(bucket + (size_t)NQ * DEG_STRIDE); // 4.98 MB
    unsigned short* Wt = (unsigned short*)(binned + (size_t)NBINS * BIN_STRIDE); // 256 KB
    int* cnt = (int*)(Wt + 2 * DQ * DQ);                                  // 64 KB
    float* dinv = (float*)(cnt + NQ);                                     // 64 KB
    int* bin_cursor = (int*)(dinv + NQ);                                  // 1 KB

    const int* src = ei;
    const int* tgt = ei + EQ;

    hipMemsetAsync(bin_cursor, 0, NBINS * sizeof(int), stream);
    k_prep_part<<<512, 256, 0, stream>>>(W, Wt, src, tgt, bin_cursor, binned);
    k_bucket_gemm<<<512, 256, 0, stream>>>(X, Wt, xwb, bin_cursor, binned,
                                           bucket, cnt, dinv);
    k_agg<<<NQ / 4, 256, 0, stream>>>((const unsigned int*)xwb, cnt, bucket,
                                      dinv, bias, out);
    k_scores<<<BQ, 256, 0, stream>>>(out, out + (size_t)NQ * DQ);
}

// Round 14
// 186.725 us; speedup vs baseline: 1.3033x; 1.0194x over previous
//
#include <hip/hip_runtime.h>

// Problem constants (match reference)
#define BQ 512
#define AQ 32
#define DQ 256
#define NQ (BQ * AQ)      // 16384 nodes
#define EQ 1048576        // edges
#define THR 0.5f
#define EPSF 1e-5f
#define DEG_STRIDE 160    // padded bucket row; deg ~ Binom(E,1/N) mean 64, +12 sigma
#define BIN_TGTS 64       // targets per bin
#define NBINS (NQ / BIN_TGTS)          // 256
#define BIN_STRIDE 4864   // mean 4096 edges/bin, sigma ~64, +12 sigma

typedef __attribute__((ext_vector_type(8))) short bf16x8;
typedef __attribute__((ext_vector_type(4))) float f32x4;

// fp32 -> bf16 round-to-nearest-even (finite inputs)
__device__ __forceinline__ unsigned short f2bf(float f) {
    unsigned int u = __float_as_uint(f);
    return (unsigned short)((u + 0x7FFFu + ((u >> 16) & 1u)) >> 16);
}
__device__ __forceinline__ float bf2f(unsigned short h) {
    return __uint_as_float((unsigned int)h << 16);
}

// ---------------------------------------------------------------------------
// Fused dispatch 1 (independent slices; bin_cursor pre-zeroed by memset):
//  blocks [0,256):    W [K,N] fp32 -> Wt hi/lo [N,K] bf16 split
//  blocks [256,512):  partition edges into 256 target-range bins, packed
//                     (t<<14|s); LDS histogram -> one global reservation per
//                     bin -> bin-grouped line-local writes.
// ---------------------------------------------------------------------------
__global__ __launch_bounds__(256) void k_prep_part(
        const float* __restrict__ W, unsigned short* __restrict__ Wt,
        const int* __restrict__ src, const int* __restrict__ tgt,
        int* __restrict__ bin_cursor, unsigned int* __restrict__ binned) {
    __shared__ int hist[NBINS];
    int tid = threadIdx.x;
    if (blockIdx.x < 256) {
        int idx = blockIdx.x * 256 + tid;       // covers DQ*DQ
        int n = idx >> 8;
        int k = idx & 255;
        float w = W[k * DQ + n];
        unsigned short h = f2bf(w);
        Wt[idx] = h;                            // hi plane
        Wt[DQ * DQ + idx] = f2bf(w - bf2f(h));  // lo plane
        return;
    }
    // ---- edge partition ----
    hist[tid] = 0;
    __syncthreads();
    int base = (blockIdx.x - 256) * 4096;
    int t[16], s[16];
    #pragma unroll
    for (int i = 0; i < 16; i++) {
        int e = base + i * 256 + tid;
        t[i] = tgt[e];
        s[i] = src[e];
        atomicAdd(&hist[t[i] >> 6], 1);
    }
    __syncthreads();
    int mine = hist[tid];
    __syncthreads();
    hist[tid] = tid * BIN_STRIDE + atomicAdd(&bin_cursor[tid], mine);
    __syncthreads();
    #pragma unroll
    for (int i = 0; i < 16; i++) {
        int slot = atomicAdd(&hist[t[i] >> 6], 1);
        binned[slot] = ((unsigned int)t[i] << 14) | (unsigned int)s[i];
    }
}

// ---------------------------------------------------------------------------
// Fused dispatch 2 (independent slices, both depend only on dispatch 1):
//  blocks [0,256):    per-bin bucket build in LDS, coalesced write-out,
//                     cnt + precomputed fp32 dinv
//  blocks [256,512):  bf16x3 split MFMA GEMM xwb = bf16(X @ W), single
//                     contiguous [NQ][256] bf16 layout (8 MB)
// ---------------------------------------------------------------------------
__global__ __launch_bounds__(256) void k_bucket_gemm(
        const float* __restrict__ Xp, const unsigned short* __restrict__ Wt,
        unsigned short* __restrict__ xwb,
        const int* __restrict__ bin_cursor, const unsigned int* __restrict__ binned,
        unsigned short* __restrict__ bucket, int* __restrict__ cnt,
        float* __restrict__ dinv) {
    __shared__ unsigned short lbuck[BIN_TGTS * DEG_STRIDE];  // 20 KB
    __shared__ int lcnt[BIN_TGTS];
    int tid = threadIdx.x;
    if (blockIdx.x < NBINS) {
        // ---- bucket build ----
        int b = blockIdx.x;
        if (tid < BIN_TGTS) lcnt[tid] = 0;
        __syncthreads();
        int beg = b * BIN_STRIDE;
        int count = bin_cursor[b];
        if (count > BIN_STRIDE) count = BIN_STRIDE;
        int end = beg + count;
        for (int i = beg + tid; i < end; i += 256) {
            unsigned int ed = binned[i];
            int tl = (int)(ed >> 14) & 63;
            int pos = atomicAdd(&lcnt[tl], 1);
            if (pos < DEG_STRIDE)
                lbuck[tl * DEG_STRIDE + pos] = (unsigned short)(ed & 0x3FFFu);
        }
        __syncthreads();
        const unsigned int* lb32 = (const unsigned int*)lbuck;   // 5120 uints
        unsigned int* gb32 = (unsigned int*)(bucket + (size_t)b * BIN_TGTS * DEG_STRIDE);
        #pragma unroll
        for (int i = 0; i < 20; i++) gb32[i * 256 + tid] = lb32[i * 256 + tid];
        if (tid < BIN_TGTS) {
            int c = lcnt[tid];
            cnt[b * BIN_TGTS + tid] = c;
            dinv[b * BIN_TGTS + tid] = rsqrtf((float)(c + 1));
        }
        return;
    }
    // ---- bf16x3 split MFMA GEMM ----
    // A frag: A[m=lane&15][k=quad*8+j]; B frag from Wt[n][k]; C/D row=quad*4+r,
    // col=lane&15 (verified rounds 5-13).
    int wave = tid >> 6;
    int lane = tid & 63;
    int col = lane & 15;
    int quad = lane >> 4;
    int mbase = (blockIdx.x - NBINS) * 64 + wave * 16;
    int m = mbase + col;

    const float* arow = Xp + (size_t)m * DQ;
    const unsigned short* Wlo = Wt + DQ * DQ;

    f32x4 acc[16];
    f32x4 zero = {0.f, 0.f, 0.f, 0.f};
    #pragma unroll
    for (int i = 0; i < 16; i++) acc[i] = zero;

    for (int k0 = 0; k0 < DQ; k0 += 32) {
        int kq = k0 + quad * 8;
        float4 a0 = *(const float4*)(arow + kq);
        float4 a1 = *(const float4*)(arow + kq + 4);
        float av[8] = {a0.x, a0.y, a0.z, a0.w, a1.x, a1.y, a1.z, a1.w};
        bf16x8 ah, al;
        #pragma unroll
        for (int j = 0; j < 8; j++) {
            unsigned short h = f2bf(av[j]);
            ah[j] = (short)h;
            al[j] = (short)f2bf(av[j] - bf2f(h));
        }
        #pragma unroll
        for (int nt = 0; nt < 16; nt++) {
            size_t boff = (size_t)(nt * 16 + col) * DQ + kq;
            bf16x8 bh = *(const bf16x8*)(Wt + boff);
            bf16x8 bl = *(const bf16x8*)(Wlo + boff);
            acc[nt] = __builtin_amdgcn_mfma_f32_16x16x32_bf16(ah, bh, acc[nt], 0, 0, 0);
            acc[nt] = __builtin_amdgcn_mfma_f32_16x16x32_bf16(al, bh, acc[nt], 0, 0, 0);
            acc[nt] = __builtin_amdgcn_mfma_f32_16x16x32_bf16(ah, bl, acc[nt], 0, 0, 0);
        }
    }

    #pragma unroll
    for (int nt = 0; nt < 16; nt++) {
        #pragma unroll
        for (int r = 0; r < 4; r++) {
            xwb[(size_t)(mbase + quad * 4 + r) * DQ + nt * 16 + col] =
                f2bf(acc[nt][r]);
        }
    }
}

// ---------------------------------------------------------------------------
// Fused aggregation + scores: one block per batch clip (512 threads, 8
// waves). Phase 1: each wave runs the round-13 gather (identical inner
// loop: one 512B uint2 row load per edge, 64-wide coalesced index/coef
// prefetch + shfl broadcast) for 4 targets sequentially, writing Xo to
// global AND to the LDS score tile (kills the 16MB global round-trip and
// one dispatch boundary). Phase 2 (after __syncthreads): the round-13
// k_scores math, 2 pairs/thread. Numerics identical to round 13.
// ---------------------------------------------------------------------------
__global__ __launch_bounds__(512) void k_agg_scores(
        const unsigned int* __restrict__ xwb,
        const int* __restrict__ cnt,
        const unsigned short* __restrict__ bucket,
        const float* __restrict__ dinv,
        const float* __restrict__ bias,
        float* __restrict__ out,      // Xo [NQ*DQ]
        float* __restrict__ mask) {   // [BQ*AQ*AQ]
    __shared__ float xs[AQ][DQ + 4];   // 33 KB; rows 1040B = 65x16B aligned
    __shared__ float sq[AQ];
    __shared__ float sc[AQ][AQ + 1];
    __shared__ float rmin[AQ], rmax[AQ];

    int tid = threadIdx.x;
    int wave = tid >> 6;              // 0..7
    int lane = tid & 63;
    int bq = blockIdx.x;              // batch clip
    const uint2* xw2 = (const uint2*)xwb;

    float4 bv = ((const float4*)bias)[lane];

    // ---- phase 1: gather 4 targets per wave ----
    #pragma unroll 1
    for (int i = 0; i < 4; i++) {
        int a = wave * 4 + i;         // actor 0..31
        int t = bq * AQ + a;
        float dt = dinv[t];
        float c0 = dt * dt;
        uint2 sp = xw2[(size_t)t * 64 + lane];
        float4 acc;
        acc.x = __uint_as_float(sp.x << 16) * c0;
        acc.y = __uint_as_float(sp.x & 0xFFFF0000u) * c0;
        acc.z = __uint_as_float(sp.y << 16) * c0;
        acc.w = __uint_as_float(sp.y & 0xFFFF0000u) * c0;

        const unsigned short* brow = bucket + t * DEG_STRIDE;
        int num = cnt[t];
        if (num > DEG_STRIDE) num = DEG_STRIDE;
        for (int k0 = 0; k0 < num; k0 += 64) {
            int rem = num - k0;
            int n = rem < 64 ? rem : 64;
            int idx = k0 + (lane < n ? lane : 0);
            int e = (int)brow[idx];               // coalesced 2B/lane prefetch
            float cl = (lane < n) ? dinv[e] * dt : 0.f;
            int n8 = (n + 7) & ~7;
            for (int j0 = 0; j0 < n8; j0 += 8) {
                #pragma unroll
                for (int jj = 0; jj < 8; jj++) {
                    int j = j0 + jj;
                    int s = __shfl(e, j);
                    float c = __shfl(cl, j);
                    uint2 p = xw2[(size_t)s * 64 + lane];
                    acc.x += __uint_as_float(p.x << 16) * c;
                    acc.y += __uint_as_float(p.x & 0xFFFF0000u) * c;
                    acc.z += __uint_as_float(p.y << 16) * c;
                    acc.w += __uint_as_float(p.y & 0xFFFF0000u) * c;
                }
            }
        }

        acc.x += bv.x; acc.y += bv.y; acc.z += bv.z; acc.w += bv.w;
        ((float4*)out)[(size_t)t * 64 + lane] = acc;
        *(float4*)&xs[a][lane * 4] = acc;
    }
    __syncthreads();

    // ---- phase 2: scores (identical math to round-13 k_scores) ----
    if (tid < AQ) {
        const float4* xi = (const float4*)xs[tid];
        float s = 0.f;
        #pragma unroll 8
        for (int dd = 0; dd < DQ / 4; dd++) {
            float4 a = xi[dd];
            s += a.x * a.x + a.y * a.y + a.z * a.z + a.w * a.w;
        }
        sq[tid] = s;
    }
    __syncthreads();

    {
        int p0 = tid * 2;             // 2 pairs per thread (1024 pairs)
        int i = p0 >> 5;
        int j0 = p0 & 31;
        const float4* xi = (const float4*)xs[i];
        float g[2] = {0.f, 0.f};
        for (int dd = 0; dd < DQ / 4; dd += 8) {
            float4 ar[8];
            #pragma unroll
            for (int u = 0; u < 8; u++) ar[u] = xi[dd + u];
            #pragma unroll
            for (int q = 0; q < 2; q++) {
                const float4* xj = (const float4*)xs[j0 + q];
                float gq = 0.f;
                #pragma unroll
                for (int u = 0; u < 8; u++) {
                    float4 b = xj[dd + u];
                    gq += ar[u].x * b.x + ar[u].y * b.y +
                          ar[u].z * b.z + ar[u].w * b.w;
                }
                g[q] += gq;
            }
        }
        #pragma unroll
        for (int q = 0; q < 2; q++) {
            sc[i][j0 + q] = sq[i] - 2.f * g[q] + sq[j0 + q];
        }
    }
    __syncthreads();

    if (tid < AQ) {
        float mn = sc[tid][0], mx = sc[tid][0];
        for (int j = 1; j < AQ; j++) {
            float v = sc[tid][j];
            mn = fminf(mn, v);
            mx = fmaxf(mx, v);
        }
        rmin[tid] = mn;
        rmax[tid] = mx;
    }
    __syncthreads();

    {
        float* mb = mask + (size_t)bq * AQ * AQ;
        int p0 = tid * 2;
        int i = p0 >> 5, j0 = p0 & 31;
        float inv = 1.0f / (rmax[i] - rmin[i] + EPSF);
        float2 mv;
        mv.x = ((sc[i][j0 + 0] - rmin[i]) * inv > THR) ? 1.0f : 0.0f;
        mv.y = ((sc[i][j0 + 1] - rmin[i]) * inv > THR) ? 1.0f : 0.0f;
        ((float2*)mb)[tid] = mv;
    }
}

// ---------------------------------------------------------------------------
extern "C" void kernel_launch(void* const* d_in, const int* in_sizes, int n_in,
                              void* d_out, int out_size, void* d_ws, size_t ws_size,
                              hipStream_t stream) {
    const float* X    = (const float*)d_in[0];   // [B,A,D]
    const int*   ei   = (const int*)d_in[1];     // [2,E]
    const float* W    = (const float*)d_in[2];   // [D,D]
    const float* bias = (const float*)d_in[3];   // [D]
    float* out = (float*)d_out;                  // [N*D] Xo  ++  [B*A*A] mask

    char* ws = (char*)d_ws;
    unsigned short* xwb = (unsigned short*)ws;                            // 8 MB
    unsigned short* bucket = (unsigned short*)(ws + (size_t)NQ * DQ * 2); // 5.25 MB
    unsigned int* binned = (unsigned int*)(bucket + (size_t)NQ * DEG_STRIDE); // 4.98 MB
    unsigned short* Wt = (unsigned short*)(binned + (size_t)NBINS * BIN_STRIDE); // 256 KB
    int* cnt = (int*)(Wt + 2 * DQ * DQ);                                  // 64 KB
    float* dinv = (float*)(cnt + NQ);                                     // 64 KB
    int* bin_cursor = (int*)(dinv + NQ);                                  // 1 KB

    const int* src = ei;
    const int* tgt = ei + EQ;

    hipMemsetAsync(bin_cursor, 0, NBINS * sizeof(int), stream);
    k_prep_part<<<512, 256, 0, stream>>>(W, Wt, src, tgt, bin_cursor, binned);
    k_bucket_gemm<<<512, 256, 0, stream>>>(X, Wt, xwb, bin_cursor, binned,
                                           bucket, cnt, dinv);
    k_agg_scores<<<BQ, 512, 0, stream>>>((const unsigned int*)xwb, cnt, bucket,
                                         dinv, bias, out,
                                         out + (size_t)NQ * DQ);
}